// Round 12
// baseline (610.916 us; speedup 1.0000x reference)
//
#include <hip/hip_runtime.h>

#define B_ROWS 8192
#define IN_DIM 2048
#define H_DIM  2048
#define K_DIM  4096              // IN + H
#define CH_OFF (B_ROWS * H_DIM)  // offset of h_t in d_out
#define NKS    (K_DIM / 64)      // 64 K-steps of depth 64
#define NIT    (NKS / 2)         // 32 iterations, 2 K-steps each

typedef __attribute__((ext_vector_type(8))) short bf16x8;
typedef __attribute__((ext_vector_type(8))) short short8;
typedef __attribute__((ext_vector_type(16))) float f32x16;

// fp32 -> bf16 round-to-nearest-even
static __device__ __forceinline__ unsigned short f2bf(float f) {
  union { float f; unsigned u; } v; v.f = f;
  unsigned r = v.u + 0x7fffu + ((v.u >> 16) & 1u);
  return (unsigned short)(r >> 16);
}

// async 16B global -> LDS (wave-uniform base + lane*16 on the LDS side).
// offset operand MUST be 0 (R7/R8/R9 NaNs with non-zero offsets).
static __device__ __forceinline__ void load_lds16(const void* g, void* l) {
  __builtin_amdgcn_global_load_lds(
      (const __attribute__((address_space(1))) unsigned int*)(unsigned long long)(uintptr_t)g,
      (__attribute__((address_space(3))) unsigned int*)(unsigned int)(uintptr_t)l,
      16, 0, 0);
}

// ---------------------------------------------------------------------------
// Pack [input | hidden] (fp32) -> A bf16 [8192][4096]
// ---------------------------------------------------------------------------
__global__ __launch_bounds__(256) void pack_act(
    const float* __restrict__ inp, const float* __restrict__ hid,
    short* __restrict__ out) {
  int idx = blockIdx.x * 256 + threadIdx.x;
  int m = idx >> 9;
  int k = (idx & 511) * 8;
  const float* s = (k < IN_DIM) ? (inp + m * IN_DIM + k)
                                : (hid + m * H_DIM + (k - IN_DIM));
  float4 a = *(const float4*)s;
  float4 c = *(const float4*)(s + 4);
  short8 o;
  o[0] = (short)f2bf(a.x); o[1] = (short)f2bf(a.y);
  o[2] = (short)f2bf(a.z); o[3] = (short)f2bf(a.w);
  o[4] = (short)f2bf(c.x); o[5] = (short)f2bf(c.y);
  o[6] = (short)f2bf(c.z); o[7] = (short)f2bf(c.w);
  *(short8*)(out + (size_t)idx * 8) = o;
}

// ---------------------------------------------------------------------------
// Pack + transpose weights -> WT[n][k] bf16, n = (h>>5)*128 + gate*32 + (h&31)
// (32-wide gate blocks so a 32x32 MFMA B-fragment = one gate; 128-wide
// groups hold the 4 gates of the same 32 h values -> lane-local epilogue.)
// ---------------------------------------------------------------------------
__global__ __launch_bounds__(256) void pack_w(
    const float* __restrict__ wi0, const float* __restrict__ wi1,
    const float* __restrict__ wi2, const float* __restrict__ wi3,
    const float* __restrict__ wh0, const float* __restrict__ wh1,
    const float* __restrict__ wh2, const float* __restrict__ wh3,
    short* __restrict__ out) {
  __shared__ float tileS[64][65];
  int b = blockIdx.x;
  int w = b >> 10;
  int tile = b & 1023;
  int tk = tile >> 5;
  int th = tile & 31;
  const float* src;
  switch (w) {
    case 0: src = wi0; break; case 1: src = wi1; break;
    case 2: src = wi2; break; case 3: src = wi3; break;
    case 4: src = wh0; break; case 5: src = wh1; break;
    case 6: src = wh2; break; default: src = wh3; break;
  }
  int g = w & 3, half = w >> 2;
  int t = threadIdx.x;
  #pragma unroll
  for (int it = 0; it < 4; ++it) {
    int idx = it * 256 + t;
    int sr = idx >> 4, sc = idx & 15;
    float4 v = *(const float4*)(src + (tk * 64 + sr) * H_DIM + th * 64 + sc * 4);
    tileS[sr][sc * 4 + 0] = v.x; tileS[sr][sc * 4 + 1] = v.y;
    tileS[sr][sc * 4 + 2] = v.z; tileS[sr][sc * 4 + 3] = v.w;
  }
  __syncthreads();
  #pragma unroll
  for (int it = 0; it < 2; ++it) {
    int idx = it * 256 + t;
    int orow = idx >> 3;
    int okg = idx & 7;
    short8 o;
    #pragma unroll
    for (int j = 0; j < 8; ++j) o[j] = (short)f2bf(tileS[okg * 8 + j][orow]);
    int hg = th * 64 + orow;
    int n = (hg >> 5) * 128 + g * 32 + (hg & 31);
    int off = n * K_DIM + half * IN_DIM + tk * 64 + okg * 8;
    *(short8*)(out + off) = o;
  }
}

// ---------------------------------------------------------------------------
// Fused GEMM (bf16 32x32x16 MFMA) + LSTM epilogue — R10's proven 8-phase
// schedule/staging, fragments and epilogue adapted to the 32x32 layout.
// Waves: 4M x 2N; per wave 64m x 128n (= 2 m-frags x 4 gate-frags of 32x32).
// ---------------------------------------------------------------------------
__global__ __launch_bounds__(512, 2) void lstm_gemm(
    const short* __restrict__ actB,   // [8192][4096] bf16
    const short* __restrict__ wB,     // [8192][4096] bf16 packed W^T
    const float* __restrict__ cprev,
    const float* __restrict__ bi_p, const float* __restrict__ bf_p,
    const float* __restrict__ bg_p, const float* __restrict__ bo_p,
    float* __restrict__ out) {
  // buf: 256 rows x 64 k x 2B = 32 KB; row = 128B = 8 chunks of 16B,
  // phys chunk = logical ^ (row & 7). 2 bufs per operand. (Unchanged.)
  __shared__ __align__(16) short As[2][16384];   // 64 KB
  __shared__ __align__(16) short Bs[2][16384];   // 64 KB

  int bid = blockIdx.x;
  int swz = (bid & 7) * 128 + (bid >> 3);   // bijective XCD swizzle (1024%8==0)
  int mblk = swz >> 5, nblk = swz & 31;
  int m0 = mblk * 256;
  int n0 = nblk * 256;

  int t = threadIdx.x;
  int lane = t & 63, wid = t >> 6;
  int wm = wid >> 1, wn = wid & 1;          // 4M x 2N wave grid
  int cl32 = lane & 31;

  // ---- staging thread map (byte-identical to R10) ----
  int rpl0 = t >> 3, c0s = t & 7;
  int cu0 = c0s ^ (rpl0 & 7);
  int idx1 = 512 + t;
  int rpl1 = idx1 >> 3, c1s = idx1 & 7;
  int cu1 = c1s ^ (rpl1 & 7);
  const short* aG0 = actB + (size_t)(m0 + rpl0) * K_DIM + cu0 * 8;
  const short* aG1 = actB + (size_t)(m0 + rpl1) * K_DIM + cu1 * 8;
  const short* bG0 = wB   + (size_t)(n0 + rpl0) * K_DIM + cu0 * 8;
  const short* bG1 = wB   + (size_t)(n0 + rpl1) * K_DIM + cu1 * 8;
  char* aL0 = (char*)&As[0][0] + t * 16;
  char* aL1 = (char*)&As[0][0] + idx1 * 16;
  char* bL0 = (char*)&Bs[0][0] + t * 16;
  char* bL1 = (char*)&Bs[0][0] + idx1 * 16;

  auto stgA = [&](int ks, int h, int buf) {
    load_lds16(aG0 + h * (128 * K_DIM) + ks * 64, aL0 + buf * 32768 + h * 16384);
    load_lds16(aG1 + h * (128 * K_DIM) + ks * 64, aL1 + buf * 32768 + h * 16384);
  };
  auto stgB = [&](int ks, int h, int buf) {
    load_lds16(bG0 + h * (128 * K_DIM) + ks * 64, bL0 + buf * 32768 + h * 16384);
    load_lds16(bG1 + h * (128 * K_DIM) + ks * 64, bL1 + buf * 32768 + h * 16384);
  };

  // ---- 32x32 fragment read bases ----
  // lane l holds row (base + l&31), k-octet (l>>5); MFMA k-slot ks uses
  // octets {2ks, 2ks+1}; phys chunk = (2ks ^ hp), hp = (l>>5)^(l&7).
  int hp = (lane >> 5) ^ (lane & 7);
  const char* aRowBase = (const char*)&As[0][0] + (wm * 64 + cl32) * 128;
  const char* bRowBase = (const char*)&Bs[0][0] + (wn * 128 + cl32) * 128;
  const char* aRdK[4]; const char* bRdK[4];
  #pragma unroll
  for (int ks = 0; ks < 4; ++ks) {
    int co = (hp ^ (2 * ks)) << 4;
    aRdK[ks] = aRowBase + co;
    bRdK[ks] = bRowBase + co;
  }

  auto rdA32 = [&](int buf, int mi, int ks) -> bf16x8 {   // args compile-time
    return *(const bf16x8*)(aRdK[ks] + buf * 32768 + mi * 4096);
  };
  auto rdB32 = [&](int buf, int g, int ks) -> bf16x8 {
    return *(const bf16x8*)(bRdK[ks] + buf * 32768 + g * 4096);
  };

  f32x16 acc[2][4];
  #pragma unroll
  for (int mi = 0; mi < 2; ++mi)
    #pragma unroll
    for (int g = 0; g < 4; ++g)
      #pragma unroll
      for (int r = 0; r < 16; ++r) acc[mi][g][r] = 0.f;

  bf16x8 aF[4], b0F[2][4], b1F[2][4];

  auto QUAD32 = [&](bf16x8 (&af)[4], bf16x8 (&bf)[2][4], int mi, int gb) {
    __builtin_amdgcn_s_setprio(1);
    #pragma unroll
    for (int gg = 0; gg < 2; ++gg)
      #pragma unroll
      for (int ks = 0; ks < 4; ++ks)
        acc[mi][gb + gg] = __builtin_amdgcn_mfma_f32_32x32x16_bf16(
            af[ks], bf[gg][ks], acc[mi][gb + gg], 0, 0, 0);
    __builtin_amdgcn_s_setprio(0);
  };

  // One K-step (4 phases), R10 schedule. bufC current, bufN next.
  // b0F (gates 0,1) for THIS step preloaded in previous P_d / prologue.
  auto halfK = [&](int bufC, int bufN, int ksA_, int bufA_, int ksB_, int bufB_) {
    // -- P_a: read A mi0 (4); stage A-h0; Q(mi0, g01) --
    #pragma unroll
    for (int ks = 0; ks < 4; ++ks) aF[ks] = rdA32(bufC, 0, ks);
    stgA(ksA_, 0, bufA_);
    asm volatile("s_waitcnt lgkmcnt(8)" ::: "memory");
    __builtin_amdgcn_s_barrier();
    asm volatile("s_waitcnt lgkmcnt(0)" ::: "memory");
    __builtin_amdgcn_sched_barrier(0);
    QUAD32(aF, b0F, 0, 0);
    __builtin_amdgcn_s_barrier();
    // -- P_b: read B gates 2,3 (8); stage A-h1; Q(mi0, g23) --
    #pragma unroll
    for (int gg = 0; gg < 2; ++gg)
      #pragma unroll
      for (int ks = 0; ks < 4; ++ks) b1F[gg][ks] = rdB32(bufC, gg + 2, ks);
    stgA(ksA_, 1, bufA_);
    __builtin_amdgcn_s_barrier();
    asm volatile("s_waitcnt lgkmcnt(0)" ::: "memory");
    __builtin_amdgcn_sched_barrier(0);
    QUAD32(aF, b1F, 0, 2);
    __builtin_amdgcn_s_barrier();
    // -- P_c: read A mi1 (4); stage B-h0; Q(mi1, g23) --
    #pragma unroll
    for (int ks = 0; ks < 4; ++ks) aF[ks] = rdA32(bufC, 1, ks);
    stgB(ksB_, 0, bufB_);
    __builtin_amdgcn_s_barrier();
    asm volatile("s_waitcnt lgkmcnt(0)" ::: "memory");
    __builtin_amdgcn_sched_barrier(0);
    QUAD32(aF, b1F, 1, 2);
    __builtin_amdgcn_s_barrier();
    // -- P_d: stage B-h1; vmcnt(4) publishes bufN; Q(mi1, g01);
    //         preload next step's b0F (gates 0,1) from bufN --
    stgB(ksB_, 1, bufB_);
    asm volatile("s_waitcnt vmcnt(4)" ::: "memory");
    __builtin_amdgcn_s_barrier();
    __builtin_amdgcn_sched_barrier(0);
    QUAD32(aF, b0F, 1, 0);
    #pragma unroll
    for (int gg = 0; gg < 2; ++gg)
      #pragma unroll
      for (int ks = 0; ks < 4; ++ks) b0F[gg][ks] = rdB32(bufN, gg, ks);
    __builtin_amdgcn_s_barrier();
  };

  // prologue (R10 order): B(0),A(0) -> buf0; B(1) -> buf1; publish tile 0
  stgB(0, 0, 0); stgB(0, 1, 0);
  stgA(0, 0, 0); stgA(0, 1, 0);
  stgB(1, 0, 1); stgB(1, 1, 1);
  asm volatile("s_waitcnt vmcnt(4)" ::: "memory");
  __builtin_amdgcn_s_barrier();
  #pragma unroll
  for (int gg = 0; gg < 2; ++gg)
    #pragma unroll
    for (int ks = 0; ks < 4; ++ks) b0F[gg][ks] = rdB32(0, gg, ks);

  #pragma unroll 1
  for (int i = 0; i < NIT; ++i) {
    int ks1 = 2 * i + 1;
    int ksA = 2 * i + 2; if (ksA > NKS - 1) ksA = NKS - 1;
    int ksB = 2 * i + 3; if (ksB > NKS - 1) ksB = NKS - 1;
    halfK(0, 1, ks1, 1, ksA, 0);   // K-step 2i   (buf0)
    halfK(1, 0, ksA, 0, ksB, 1);   // K-step 2i+1 (buf1)
  }
  asm volatile("s_waitcnt vmcnt(0)" ::: "memory");

  // ---- epilogue: lane-local i,f,g,o; 128B-contiguous stores ----
  int hg = nblk * 64 + wn * 32 + cl32;
  float vbi = bi_p[hg], vbf = bf_p[hg], vbg = bg_p[hg], vbo = bo_p[hg];
  int mrow = m0 + wm * 64 + 4 * (lane >> 5);
  #pragma unroll
  for (int mi = 0; mi < 2; ++mi) {
    #pragma unroll
    for (int r = 0; r < 16; ++r) {
      int mg = mrow + mi * 32 + (r & 3) + 8 * (r >> 2);
      float pi = acc[mi][0][r] + vbi;
      float pf = acc[mi][1][r] + vbf;
      float pg = acc[mi][2][r] + vbg;
      float po = acc[mi][3][r] + vbo;
      float iv = 1.f / (1.f + __expf(-pi));
      float fv = 1.f / (1.f + __expf(-pf));
      float gv = 1.f - 2.f / (__expf(2.f * pg) + 1.f);
      float ov = 1.f / (1.f + __expf(-po));
      float cp = cprev[(size_t)mg * H_DIM + hg];
      float cv = fv * cp + iv * gv;
      float tc = 1.f - 2.f / (__expf(2.f * cv) + 1.f);
      out[(size_t)mg * H_DIM + hg] = cv;
      out[CH_OFF + (size_t)mg * H_DIM + hg] = ov * tc;
    }
  }
}

extern "C" void kernel_launch(void* const* d_in, const int* in_sizes, int n_in,
                              void* d_out, int out_size, void* d_ws, size_t ws_size,
                              hipStream_t stream) {
  const float* inp   = (const float*)d_in[0];
  const float* hid   = (const float*)d_in[1];
  const float* cprev = (const float*)d_in[2];
  short* actB = (short*)d_ws;
  short* wB   = actB + (size_t)B_ROWS * K_DIM;

  pack_act<<<dim3(B_ROWS * K_DIM / 8 / 256), dim3(256), 0, stream>>>(inp, hid, actB);
  pack_w<<<dim3(8 * 1024), dim3(256), 0, stream>>>(
      (const float*)d_in[3], (const float*)d_in[4],
      (const float*)d_in[5], (const float*)d_in[6],
      (const float*)d_in[7], (const float*)d_in[8],
      (const float*)d_in[9], (const float*)d_in[10], wB);
  lstm_gemm<<<dim3(1024), dim3(512), 0, stream>>>(
      actB, wB, cprev,
      (const float*)d_in[11], (const float*)d_in[12],
      (const float*)d_in[13], (const float*)d_in[14],
      (float*)d_out);
}

// Round 13
// 579.546 us; speedup vs baseline: 1.0541x; 1.0541x over previous
//
#include <hip/hip_runtime.h>

#define B_ROWS 8192
#define IN_DIM 2048
#define H_DIM  2048
#define K_DIM  4096              // IN + H
#define CH_OFF (B_ROWS * H_DIM)  // offset of h_t in d_out
#define NKS    (K_DIM / 64)      // 64 K-steps of depth 64
#define NIT    (NKS / 2)         // 32 iterations, 2 K-steps each

typedef __attribute__((ext_vector_type(8))) short bf16x8;
typedef __attribute__((ext_vector_type(8))) short short8;
typedef __attribute__((ext_vector_type(4))) float f32x4;

// fp32 -> bf16 round-to-nearest-even
static __device__ __forceinline__ unsigned short f2bf(float f) {
  union { float f; unsigned u; } v; v.f = f;
  unsigned r = v.u + 0x7fffu + ((v.u >> 16) & 1u);
  return (unsigned short)(r >> 16);
}

// async 16B global -> LDS (wave-uniform base + lane*16 on the LDS side).
// offset operand MUST be 0 (R7/R8/R9 NaNs with non-zero offsets).
static __device__ __forceinline__ void load_lds16(const void* g, void* l) {
  __builtin_amdgcn_global_load_lds(
      (const __attribute__((address_space(1))) unsigned int*)(unsigned long long)(uintptr_t)g,
      (__attribute__((address_space(3))) unsigned int*)(unsigned int)(uintptr_t)l,
      16, 0, 0);
}

// ---------------------------------------------------------------------------
// Merged pack kernel.
// blocks [0, 16384): pack [input|hidden] fp32 -> A bf16 [8192][4096]
// blocks [16384, 24576): pack+transpose weights ->
//   WT[n][k] bf16, n = (h>>4)*64 + gate*16 + (h&15)
// ---------------------------------------------------------------------------
__global__ __launch_bounds__(256) void pack_all(
    const float* __restrict__ inp, const float* __restrict__ hid,
    const float* __restrict__ wi0, const float* __restrict__ wi1,
    const float* __restrict__ wi2, const float* __restrict__ wi3,
    const float* __restrict__ wh0, const float* __restrict__ wh1,
    const float* __restrict__ wh2, const float* __restrict__ wh3,
    short* __restrict__ actB, short* __restrict__ wB) {
  __shared__ float tileS[64][65];
  int t = threadIdx.x;
  if (blockIdx.x < 16384) {
    int idx = blockIdx.x * 256 + t;
    int m = idx >> 9;
    int k = (idx & 511) * 8;
    const float* s = (k < IN_DIM) ? (inp + m * IN_DIM + k)
                                  : (hid + m * H_DIM + (k - IN_DIM));
    float4 a = *(const float4*)s;
    float4 c = *(const float4*)(s + 4);
    short8 o;
    o[0] = (short)f2bf(a.x); o[1] = (short)f2bf(a.y);
    o[2] = (short)f2bf(a.z); o[3] = (short)f2bf(a.w);
    o[4] = (short)f2bf(c.x); o[5] = (short)f2bf(c.y);
    o[6] = (short)f2bf(c.z); o[7] = (short)f2bf(c.w);
    *(short8*)(actB + (size_t)idx * 8) = o;
    return;
  }
  int b = blockIdx.x - 16384;
  int w = b >> 10;
  int tile = b & 1023;
  int tk = tile >> 5;
  int th = tile & 31;
  const float* src;
  switch (w) {
    case 0: src = wi0; break; case 1: src = wi1; break;
    case 2: src = wi2; break; case 3: src = wi3; break;
    case 4: src = wh0; break; case 5: src = wh1; break;
    case 6: src = wh2; break; default: src = wh3; break;
  }
  int g = w & 3, half = w >> 2;
  #pragma unroll
  for (int it = 0; it < 4; ++it) {
    int idx = it * 256 + t;
    int sr = idx >> 4, sc = idx & 15;
    float4 v = *(const float4*)(src + (tk * 64 + sr) * H_DIM + th * 64 + sc * 4);
    tileS[sr][sc * 4 + 0] = v.x; tileS[sr][sc * 4 + 1] = v.y;
    tileS[sr][sc * 4 + 2] = v.z; tileS[sr][sc * 4 + 3] = v.w;
  }
  __syncthreads();
  #pragma unroll
  for (int it = 0; it < 2; ++it) {
    int idx = it * 256 + t;
    int orow = idx >> 3;
    int okg = idx & 7;
    short8 o;
    #pragma unroll
    for (int j = 0; j < 8; ++j) o[j] = (short)f2bf(tileS[okg * 8 + j][orow]);
    int hg = th * 64 + orow;
    int n = (hg >> 4) * 64 + g * 16 + (hg & 15);
    int off = n * K_DIM + half * IN_DIM + tk * 64 + okg * 8;
    *(short8*)(wB + off) = o;
  }
}

// ---------------------------------------------------------------------------
// Fused GEMM (bf16 16x16x32 MFMA) + LSTM epilogue — R10's proven schedule
// with P_b+P_c merged (6 barriers/K-step) and batched cprev prefetch.
// ---------------------------------------------------------------------------
__global__ __launch_bounds__(512, 2) void lstm_gemm(
    const short* __restrict__ actB,   // [8192][4096] bf16
    const short* __restrict__ wB,     // [8192][4096] bf16 packed W^T
    const float* __restrict__ cprev,
    const float* __restrict__ bi_p, const float* __restrict__ bf_p,
    const float* __restrict__ bg_p, const float* __restrict__ bo_p,
    float* __restrict__ out) {
  // buf: 256 rows x 64 k x 2B = 32 KB; row = 128B = 8 chunks of 16B,
  // phys chunk = logical ^ (row & 7). 2 bufs per operand.
  __shared__ __align__(16) short As[2][16384];   // 64 KB
  __shared__ __align__(16) short Bs[2][16384];   // 64 KB

  int bid = blockIdx.x;
  int swz = (bid & 7) * 128 + (bid >> 3);   // bijective XCD swizzle (1024%8==0)
  int mblk = swz >> 5, nblk = swz & 31;
  int m0 = mblk * 256;
  int n0 = nblk * 256;

  int t = threadIdx.x;
  int lane = t & 63, wid = t >> 6;
  int wm = wid >> 2, wn = wid & 3;          // 2M x 4N wave grid
  int q = lane >> 4, cl = lane & 15;

  // ---- staging thread map: idx = ld*512+t covers one half-tile (128r x 8c)
  int rpl0 = t >> 3, c0s = t & 7;
  int cu0 = c0s ^ (rpl0 & 7);
  int idx1 = 512 + t;
  int rpl1 = idx1 >> 3, c1s = idx1 & 7;
  int cu1 = c1s ^ (rpl1 & 7);
  const short* aG0 = actB + (size_t)(m0 + rpl0) * K_DIM + cu0 * 8;
  const short* aG1 = actB + (size_t)(m0 + rpl1) * K_DIM + cu1 * 8;
  const short* bG0 = wB   + (size_t)(n0 + rpl0) * K_DIM + cu0 * 8;
  const short* bG1 = wB   + (size_t)(n0 + rpl1) * K_DIM + cu1 * 8;
  char* aL0 = (char*)&As[0][0] + t * 16;
  char* aL1 = (char*)&As[0][0] + idx1 * 16;
  char* bL0 = (char*)&Bs[0][0] + t * 16;
  char* bL1 = (char*)&Bs[0][0] + idx1 * 16;

  auto stgA = [&](int ks, int h, int buf) {   // h,buf compile-time at call
    load_lds16(aG0 + h * (128 * K_DIM) + ks * 64, aL0 + buf * 32768 + h * 16384);
    load_lds16(aG1 + h * (128 * K_DIM) + ks * 64, aL1 + buf * 32768 + h * 16384);
  };
  auto stgB = [&](int ks, int h, int buf) {
    load_lds16(bG0 + h * (128 * K_DIM) + ks * 64, bL0 + buf * 32768 + h * 16384);
    load_lds16(bG1 + h * (128 * K_DIM) + ks * 64, bL1 + buf * 32768 + h * 16384);
  };

  // ---- fragment read bases: row r byte = r*128, chunk = (s*4+q)^(r&7) ----
  int cc0 = (q ^ (cl & 7)) * 16;
  const char* aRd0 = (const char*)&As[0][0] + wm * 16384 + cl * 128 + cc0;
  const char* aRd1 = (const char*)&As[0][0] + wm * 16384 + cl * 128 + (cc0 ^ 64);
  const char* bRd0 = (const char*)&Bs[0][0] + wn * 8192 + cl * 128 + cc0;
  const char* bRd1 = (const char*)&Bs[0][0] + wn * 8192 + cl * 128 + (cc0 ^ 64);

  auto rdA = [&](int buf, int mi, int s) -> bf16x8 {   // all args compile-time
    return *(const bf16x8*)((s ? aRd1 : aRd0) + buf * 32768 + mi * 2048);
  };
  auto rdB = [&](int buf, int ni, int s) -> bf16x8 {
    return *(const bf16x8*)((s ? bRd1 : bRd0) + buf * 32768 + ni * 2048);
  };

  f32x4 zero = {0.f, 0.f, 0.f, 0.f};
  f32x4 acc[8][4];
  #pragma unroll
  for (int mi = 0; mi < 8; ++mi)
    #pragma unroll
    for (int ni = 0; ni < 4; ++ni) acc[mi][ni] = zero;

  bf16x8 aLo[4][2], aHi[4][2], b0f[2][2], b1f[2][2];

  auto QUAD = [&](bf16x8 (&af)[4][2], bf16x8 (&bf)[2][2], int mb, int nb) {
    __builtin_amdgcn_s_setprio(1);
    #pragma unroll
    for (int mi = 0; mi < 4; ++mi)
      #pragma unroll
      for (int ni = 0; ni < 2; ++ni)
        #pragma unroll
        for (int s = 0; s < 2; ++s)
          acc[mb + mi][nb + ni] = __builtin_amdgcn_mfma_f32_16x16x32_bf16(
              af[mi][s], bf[ni][s], acc[mb + mi][nb + ni], 0, 0, 0);
    __builtin_amdgcn_s_setprio(0);
  };

  // One K-step (3 phases, 6 barriers). bufC = current, bufN = next.
  // aLo read in P_a; b0f preloaded in previous P_d (or prologue).
  auto halfK = [&](int bufC, int bufN, int ksA_, int bufA_, int ksB_, int bufB_) {
    // -- P_a: read A-lo(8); stage A-h0; Q00(aLo,b0) --
    #pragma unroll
    for (int mi = 0; mi < 4; ++mi) {
      aLo[mi][0] = rdA(bufC, mi, 0); aLo[mi][1] = rdA(bufC, mi, 1);
    }
    stgA(ksA_, 0, bufA_);
    asm volatile("s_waitcnt lgkmcnt(8)" ::: "memory");
    __builtin_amdgcn_s_barrier();
    asm volatile("s_waitcnt lgkmcnt(0)" ::: "memory");
    __builtin_amdgcn_sched_barrier(0);
    QUAD(aLo, b0f, 0, 0);
    __builtin_amdgcn_s_barrier();
    // -- P_bc: read b1(4)+A-hi(8); stage A-h1 + B-h0; Q01, Q11 --
    #pragma unroll
    for (int ni = 0; ni < 2; ++ni) {
      b1f[ni][0] = rdB(bufC, ni + 2, 0); b1f[ni][1] = rdB(bufC, ni + 2, 1);
    }
    #pragma unroll
    for (int mi = 0; mi < 4; ++mi) {
      aHi[mi][0] = rdA(bufC, mi + 4, 0); aHi[mi][1] = rdA(bufC, mi + 4, 1);
    }
    stgA(ksA_, 1, bufA_);
    stgB(ksB_, 0, bufB_);
    asm volatile("s_waitcnt lgkmcnt(8)" ::: "memory");
    __builtin_amdgcn_s_barrier();
    asm volatile("s_waitcnt lgkmcnt(0)" ::: "memory");
    __builtin_amdgcn_sched_barrier(0);
    QUAD(aLo, b1f, 0, 2);
    QUAD(aHi, b1f, 4, 2);
    __builtin_amdgcn_s_barrier();
    // -- P_d: stage B-h1; vmcnt(4) publishes bufN; Q10(aHi,b0);
    //         preload next step's b0 from bufN under Q10's shadow --
    stgB(ksB_, 1, bufB_);
    asm volatile("s_waitcnt vmcnt(4)" ::: "memory");
    __builtin_amdgcn_s_barrier();
    __builtin_amdgcn_sched_barrier(0);
    QUAD(aHi, b0f, 4, 0);
    #pragma unroll
    for (int ni = 0; ni < 2; ++ni) {
      b0f[ni][0] = rdB(bufN, ni, 0); b0f[ni][1] = rdB(bufN, ni, 1);
    }
    __builtin_amdgcn_s_barrier();
  };

  // prologue (R10 order): B(0),A(0) -> buf0; B(1) -> buf1; publish tile 0
  stgB(0, 0, 0); stgB(0, 1, 0);
  stgA(0, 0, 0); stgA(0, 1, 0);
  stgB(1, 0, 1); stgB(1, 1, 1);
  asm volatile("s_waitcnt vmcnt(4)" ::: "memory");
  __builtin_amdgcn_s_barrier();
  // preload b0 for K-step 0 (tile 0, buf0)
  #pragma unroll
  for (int ni = 0; ni < 2; ++ni) {
    b0f[ni][0] = rdB(0, ni, 0); b0f[ni][1] = rdB(0, ni, 1);
  }

  #pragma unroll 1
  for (int i = 0; i < NIT; ++i) {
    int ks1 = 2 * i + 1;
    int ksA = 2 * i + 2; if (ksA > NKS - 1) ksA = NKS - 1;
    int ksB = 2 * i + 3; if (ksB > NKS - 1) ksB = NKS - 1;
    halfK(0, 1, ks1, 1, ksA, 0);   // K-step 2i   (buf0); stage A(2i+1), B(2i+2)
    halfK(1, 0, ksA, 0, ksB, 1);   // K-step 2i+1 (buf1); stage A(2i+2), B(2i+3)
  }

  // ---- epilogue: batch cprev loads so they fly during the vmcnt drain ----
  int hg = (nblk * 4 + wn) * 16 + cl;
  int mbase = m0 + wm * 128;
  float cp[8][4];
  #pragma unroll
  for (int mi = 0; mi < 8; ++mi)
    #pragma unroll
    for (int r = 0; r < 4; ++r)
      cp[mi][r] = cprev[(size_t)(mbase + mi * 16 + q * 4 + r) * H_DIM + hg];
  asm volatile("s_waitcnt vmcnt(0)" ::: "memory");   // retire garbage stages

  float vbi = bi_p[hg], vbf = bf_p[hg], vbg = bg_p[hg], vbo = bo_p[hg];
  #pragma unroll
  for (int mi = 0; mi < 8; ++mi) {
    #pragma unroll
    for (int r = 0; r < 4; ++r) {
      int mg = mbase + mi * 16 + q * 4 + r;
      float pi = acc[mi][0][r] + vbi;
      float pf = acc[mi][1][r] + vbf;
      float pg = acc[mi][2][r] + vbg;
      float po = acc[mi][3][r] + vbo;
      float iv = 1.f / (1.f + __expf(-pi));
      float fv = 1.f / (1.f + __expf(-pf));
      float gv = 1.f - 2.f / (__expf(2.f * pg) + 1.f);
      float ov = 1.f / (1.f + __expf(-po));
      float cv = fv * cp[mi][r] + iv * gv;
      float tc = 1.f - 2.f / (__expf(2.f * cv) + 1.f);
      out[(size_t)mg * H_DIM + hg] = cv;
      out[CH_OFF + (size_t)mg * H_DIM + hg] = ov * tc;
    }
  }
}

extern "C" void kernel_launch(void* const* d_in, const int* in_sizes, int n_in,
                              void* d_out, int out_size, void* d_ws, size_t ws_size,
                              hipStream_t stream) {
  const float* inp   = (const float*)d_in[0];
  const float* hid   = (const float*)d_in[1];
  const float* cprev = (const float*)d_in[2];
  short* actB = (short*)d_ws;
  short* wB   = actB + (size_t)B_ROWS * K_DIM;

  pack_all<<<dim3(24576), dim3(256), 0, stream>>>(
      inp, hid,
      (const float*)d_in[3], (const float*)d_in[4],
      (const float*)d_in[5], (const float*)d_in[6],
      (const float*)d_in[7], (const float*)d_in[8],
      (const float*)d_in[9], (const float*)d_in[10],
      actB, wB);
  lstm_gemm<<<dim3(1024), dim3(512), 0, stream>>>(
      actB, wB, cprev,
      (const float*)d_in[11], (const float*)d_in[12],
      (const float*)d_in[13], (const float*)d_in[14],
      (float*)d_out);
}

// Round 14
// 557.373 us; speedup vs baseline: 1.0961x; 1.0398x over previous
//
#include <hip/hip_runtime.h>

#define B_ROWS 8192
#define IN_DIM 2048
#define H_DIM  2048
#define K_DIM  4096              // IN + H
#define CH_OFF (B_ROWS * H_DIM)  // offset of h_t in d_out
#define NKS    (K_DIM / 64)      // 64 K-steps of depth 64
#define NIT    (NKS / 2)         // 32 iterations, 2 K-steps each

typedef __attribute__((ext_vector_type(8))) short bf16x8;
typedef __attribute__((ext_vector_type(8))) short short8;
typedef __attribute__((ext_vector_type(4))) float f32x4;

// fp32 -> bf16 round-to-nearest-even
static __device__ __forceinline__ unsigned short f2bf(float f) {
  union { float f; unsigned u; } v; v.f = f;
  unsigned r = v.u + 0x7fffu + ((v.u >> 16) & 1u);
  return (unsigned short)(r >> 16);
}

// async 16B global -> LDS (wave-uniform base + lane*16 on the LDS side).
// offset operand MUST be 0 (R7/R8/R9 NaNs with non-zero offsets).
static __device__ __forceinline__ void load_lds16(const void* g, void* l) {
  __builtin_amdgcn_global_load_lds(
      (const __attribute__((address_space(1))) unsigned int*)(unsigned long long)(uintptr_t)g,
      (__attribute__((address_space(3))) unsigned int*)(unsigned int)(uintptr_t)l,
      16, 0, 0);
}

// ---------------------------------------------------------------------------
// Merged pack kernel.
// blocks [0, 16384): pack [input|hidden] fp32 -> A bf16 [8192][4096]
// blocks [16384, 24576): pack+transpose weights ->
//   WT[n][k] bf16, n = (h>>4)*64 + gate*16 + (h&15)
// ---------------------------------------------------------------------------
__global__ __launch_bounds__(256) void pack_all(
    const float* __restrict__ inp, const float* __restrict__ hid,
    const float* __restrict__ wi0, const float* __restrict__ wi1,
    const float* __restrict__ wi2, const float* __restrict__ wi3,
    const float* __restrict__ wh0, const float* __restrict__ wh1,
    const float* __restrict__ wh2, const float* __restrict__ wh3,
    short* __restrict__ actB, short* __restrict__ wB) {
  __shared__ float tileS[64][65];
  int t = threadIdx.x;
  if (blockIdx.x < 16384) {
    int idx = blockIdx.x * 256 + t;
    int m = idx >> 9;
    int k = (idx & 511) * 8;
    const float* s = (k < IN_DIM) ? (inp + m * IN_DIM + k)
                                  : (hid + m * H_DIM + (k - IN_DIM));
    float4 a = *(const float4*)s;
    float4 c = *(const float4*)(s + 4);
    short8 o;
    o[0] = (short)f2bf(a.x); o[1] = (short)f2bf(a.y);
    o[2] = (short)f2bf(a.z); o[3] = (short)f2bf(a.w);
    o[4] = (short)f2bf(c.x); o[5] = (short)f2bf(c.y);
    o[6] = (short)f2bf(c.z); o[7] = (short)f2bf(c.w);
    *(short8*)(actB + (size_t)idx * 8) = o;
    return;
  }
  int b = blockIdx.x - 16384;
  int w = b >> 10;
  int tile = b & 1023;
  int tk = tile >> 5;
  int th = tile & 31;
  const float* src;
  switch (w) {
    case 0: src = wi0; break; case 1: src = wi1; break;
    case 2: src = wi2; break; case 3: src = wi3; break;
    case 4: src = wh0; break; case 5: src = wh1; break;
    case 6: src = wh2; break; default: src = wh3; break;
  }
  int g = w & 3, half = w >> 2;
  #pragma unroll
  for (int it = 0; it < 4; ++it) {
    int idx = it * 256 + t;
    int sr = idx >> 4, sc = idx & 15;
    float4 v = *(const float4*)(src + (tk * 64 + sr) * H_DIM + th * 64 + sc * 4);
    tileS[sr][sc * 4 + 0] = v.x; tileS[sr][sc * 4 + 1] = v.y;
    tileS[sr][sc * 4 + 2] = v.z; tileS[sr][sc * 4 + 3] = v.w;
  }
  __syncthreads();
  #pragma unroll
  for (int it = 0; it < 2; ++it) {
    int idx = it * 256 + t;
    int orow = idx >> 3;
    int okg = idx & 7;
    short8 o;
    #pragma unroll
    for (int j = 0; j < 8; ++j) o[j] = (short)f2bf(tileS[okg * 8 + j][orow]);
    int hg = th * 64 + orow;
    int n = (hg >> 4) * 64 + g * 16 + (hg & 15);
    int off = n * K_DIM + half * IN_DIM + tk * 64 + okg * 8;
    *(short8*)(wB + off) = o;
  }
}

// ---------------------------------------------------------------------------
// Fused GEMM (bf16 16x16x32 MFMA) + LSTM epilogue — R10's exact 8-phase
// quadrant schedule (best verified), with batched cprev prefetch.
// ---------------------------------------------------------------------------
__global__ __launch_bounds__(512, 2) void lstm_gemm(
    const short* __restrict__ actB,   // [8192][4096] bf16
    const short* __restrict__ wB,     // [8192][4096] bf16 packed W^T
    const float* __restrict__ cprev,
    const float* __restrict__ bi_p, const float* __restrict__ bf_p,
    const float* __restrict__ bg_p, const float* __restrict__ bo_p,
    float* __restrict__ out) {
  // buf: 256 rows x 64 k x 2B = 32 KB; row = 128B = 8 chunks of 16B,
  // phys chunk = logical ^ (row & 7). 2 bufs per operand.
  __shared__ __align__(16) short As[2][16384];   // 64 KB
  __shared__ __align__(16) short Bs[2][16384];   // 64 KB

  int bid = blockIdx.x;
  int swz = (bid & 7) * 128 + (bid >> 3);   // bijective XCD swizzle (1024%8==0)
  int mblk = swz >> 5, nblk = swz & 31;
  int m0 = mblk * 256;
  int n0 = nblk * 256;

  int t = threadIdx.x;
  int lane = t & 63, wid = t >> 6;
  int wm = wid >> 2, wn = wid & 3;          // 2M x 4N wave grid
  int q = lane >> 4, cl = lane & 15;

  // ---- staging thread map: idx = ld*512+t covers one half-tile (128r x 8c)
  int rpl0 = t >> 3, c0s = t & 7;
  int cu0 = c0s ^ (rpl0 & 7);
  int idx1 = 512 + t;
  int rpl1 = idx1 >> 3, c1s = idx1 & 7;
  int cu1 = c1s ^ (rpl1 & 7);
  const short* aG0 = actB + (size_t)(m0 + rpl0) * K_DIM + cu0 * 8;
  const short* aG1 = actB + (size_t)(m0 + rpl1) * K_DIM + cu1 * 8;
  const short* bG0 = wB   + (size_t)(n0 + rpl0) * K_DIM + cu0 * 8;
  const short* bG1 = wB   + (size_t)(n0 + rpl1) * K_DIM + cu1 * 8;
  char* aL0 = (char*)&As[0][0] + t * 16;
  char* aL1 = (char*)&As[0][0] + idx1 * 16;
  char* bL0 = (char*)&Bs[0][0] + t * 16;
  char* bL1 = (char*)&Bs[0][0] + idx1 * 16;

  auto stgA = [&](int ks, int h, int buf) {   // h,buf compile-time at call
    load_lds16(aG0 + h * (128 * K_DIM) + ks * 64, aL0 + buf * 32768 + h * 16384);
    load_lds16(aG1 + h * (128 * K_DIM) + ks * 64, aL1 + buf * 32768 + h * 16384);
  };
  auto stgB = [&](int ks, int h, int buf) {
    load_lds16(bG0 + h * (128 * K_DIM) + ks * 64, bL0 + buf * 32768 + h * 16384);
    load_lds16(bG1 + h * (128 * K_DIM) + ks * 64, bL1 + buf * 32768 + h * 16384);
  };

  // ---- fragment read bases: row r byte = r*128, chunk = (s*4+q)^(r&7) ----
  int cc0 = (q ^ (cl & 7)) * 16;
  const char* aRd0 = (const char*)&As[0][0] + wm * 16384 + cl * 128 + cc0;
  const char* aRd1 = (const char*)&As[0][0] + wm * 16384 + cl * 128 + (cc0 ^ 64);
  const char* bRd0 = (const char*)&Bs[0][0] + wn * 8192 + cl * 128 + cc0;
  const char* bRd1 = (const char*)&Bs[0][0] + wn * 8192 + cl * 128 + (cc0 ^ 64);

  auto rdA = [&](int buf, int mi, int s) -> bf16x8 {   // all args compile-time
    return *(const bf16x8*)((s ? aRd1 : aRd0) + buf * 32768 + mi * 2048);
  };
  auto rdB = [&](int buf, int ni, int s) -> bf16x8 {
    return *(const bf16x8*)((s ? bRd1 : bRd0) + buf * 32768 + ni * 2048);
  };

  f32x4 zero = {0.f, 0.f, 0.f, 0.f};
  f32x4 acc[8][4];
  #pragma unroll
  for (int mi = 0; mi < 8; ++mi)
    #pragma unroll
    for (int ni = 0; ni < 4; ++ni) acc[mi][ni] = zero;

  bf16x8 aLo[4][2], aHi[4][2], b0f[2][2], b1f[2][2];

  auto QUAD = [&](bf16x8 (&af)[4][2], bf16x8 (&bf)[2][2], int mb, int nb) {
    __builtin_amdgcn_s_setprio(1);
    #pragma unroll
    for (int mi = 0; mi < 4; ++mi)
      #pragma unroll
      for (int ni = 0; ni < 2; ++ni)
        #pragma unroll
        for (int s = 0; s < 2; ++s)
          acc[mb + mi][nb + ni] = __builtin_amdgcn_mfma_f32_16x16x32_bf16(
              af[mi][s], bf[ni][s], acc[mb + mi][nb + ni], 0, 0, 0);
    __builtin_amdgcn_s_setprio(0);
  };

  // One K-step (4 phases). bufC = current buffer; bufN = next K-step's.
  // b0f for THIS step preloaded in the previous P_d (or prologue).
  auto halfK = [&](int bufC, int bufN, int ksA_, int bufA_, int ksB_, int bufB_) {
    // -- P_a: read A-lo(8); stage A-h0; Q00(aLo,b0) --
    #pragma unroll
    for (int mi = 0; mi < 4; ++mi) {
      aLo[mi][0] = rdA(bufC, mi, 0); aLo[mi][1] = rdA(bufC, mi, 1);
    }
    stgA(ksA_, 0, bufA_);
    asm volatile("s_waitcnt lgkmcnt(8)" ::: "memory");
    __builtin_amdgcn_s_barrier();
    asm volatile("s_waitcnt lgkmcnt(0)" ::: "memory");
    __builtin_amdgcn_sched_barrier(0);
    QUAD(aLo, b0f, 0, 0);
    __builtin_amdgcn_s_barrier();
    // -- P_b: read B1(4); stage A-h1; Q01(aLo,b1) --
    #pragma unroll
    for (int ni = 0; ni < 2; ++ni) {
      b1f[ni][0] = rdB(bufC, ni + 2, 0); b1f[ni][1] = rdB(bufC, ni + 2, 1);
    }
    stgA(ksA_, 1, bufA_);
    __builtin_amdgcn_s_barrier();
    asm volatile("s_waitcnt lgkmcnt(0)" ::: "memory");
    __builtin_amdgcn_sched_barrier(0);
    QUAD(aLo, b1f, 0, 2);
    __builtin_amdgcn_s_barrier();
    // -- P_c: read A-hi(8); stage B-h0; Q11(aHi,b1) --
    #pragma unroll
    for (int mi = 0; mi < 4; ++mi) {
      aHi[mi][0] = rdA(bufC, mi + 4, 0); aHi[mi][1] = rdA(bufC, mi + 4, 1);
    }
    stgB(ksB_, 0, bufB_);
    __builtin_amdgcn_s_barrier();
    asm volatile("s_waitcnt lgkmcnt(0)" ::: "memory");
    __builtin_amdgcn_sched_barrier(0);
    QUAD(aHi, b1f, 4, 2);
    __builtin_amdgcn_s_barrier();
    // -- P_d: stage B-h1; vmcnt(4) publishes bufN; Q10(aHi,b0);
    //         preload next step's b0 from bufN under Q10's shadow --
    stgB(ksB_, 1, bufB_);
    asm volatile("s_waitcnt vmcnt(4)" ::: "memory");
    __builtin_amdgcn_s_barrier();
    __builtin_amdgcn_sched_barrier(0);
    QUAD(aHi, b0f, 4, 0);
    #pragma unroll
    for (int ni = 0; ni < 2; ++ni) {
      b0f[ni][0] = rdB(bufN, ni, 0); b0f[ni][1] = rdB(bufN, ni, 1);
    }
    __builtin_amdgcn_s_barrier();
  };

  // prologue: stage B(0), A(0) -> buf0; B(1) -> buf1; publish tile 0
  stgB(0, 0, 0); stgB(0, 1, 0);
  stgA(0, 0, 0); stgA(0, 1, 0);
  stgB(1, 0, 1); stgB(1, 1, 1);
  asm volatile("s_waitcnt vmcnt(4)" ::: "memory");
  __builtin_amdgcn_s_barrier();
  // preload b0 for K-step 0 (tile 0, buf0)
  #pragma unroll
  for (int ni = 0; ni < 2; ++ni) {
    b0f[ni][0] = rdB(0, ni, 0); b0f[ni][1] = rdB(0, ni, 1);
  }

  #pragma unroll 1
  for (int i = 0; i < NIT; ++i) {
    int ks1 = 2 * i + 1;
    int ksA = 2 * i + 2; if (ksA > NKS - 1) ksA = NKS - 1;
    int ksB = 2 * i + 3; if (ksB > NKS - 1) ksB = NKS - 1;
    halfK(0, 1, ks1, 1, ksA, 0);   // K-step 2i   (buf0); stage A(2i+1), B(2i+2)
    halfK(1, 0, ksA, 0, ksB, 1);   // K-step 2i+1 (buf1); stage A(2i+2), B(2i+3)
  }

  // ---- epilogue: batch cprev loads so they fly during the vmcnt drain ----
  int hg = (nblk * 4 + wn) * 16 + cl;
  int mbase = m0 + wm * 128;
  float cp[8][4];
  #pragma unroll
  for (int mi = 0; mi < 8; ++mi)
    #pragma unroll
    for (int r = 0; r < 4; ++r)
      cp[mi][r] = cprev[(size_t)(mbase + mi * 16 + q * 4 + r) * H_DIM + hg];
  asm volatile("s_waitcnt vmcnt(0)" ::: "memory");   // retire garbage stages

  float vbi = bi_p[hg], vbf = bf_p[hg], vbg = bg_p[hg], vbo = bo_p[hg];
  #pragma unroll
  for (int mi = 0; mi < 8; ++mi) {
    #pragma unroll
    for (int r = 0; r < 4; ++r) {
      int mg = mbase + mi * 16 + q * 4 + r;
      float pi = acc[mi][0][r] + vbi;
      float pf = acc[mi][1][r] + vbf;
      float pg = acc[mi][2][r] + vbg;
      float po = acc[mi][3][r] + vbo;
      float iv = 1.f / (1.f + __expf(-pi));
      float fv = 1.f / (1.f + __expf(-pf));
      float gv = 1.f - 2.f / (__expf(2.f * pg) + 1.f);
      float ov = 1.f / (1.f + __expf(-po));
      float cv = fv * cp[mi][r] + iv * gv;
      float tc = 1.f - 2.f / (__expf(2.f * cv) + 1.f);
      out[(size_t)mg * H_DIM + hg] = cv;
      out[CH_OFF + (size_t)mg * H_DIM + hg] = ov * tc;
    }
  }
}

extern "C" void kernel_launch(void* const* d_in, const int* in_sizes, int n_in,
                              void* d_out, int out_size, void* d_ws, size_t ws_size,
                              hipStream_t stream) {
  const float* inp   = (const float*)d_in[0];
  const float* hid   = (const float*)d_in[1];
  const float* cprev = (const float*)d_in[2];
  short* actB = (short*)d_ws;
  short* wB   = actB + (size_t)B_ROWS * K_DIM;

  pack_all<<<dim3(24576), dim3(256), 0, stream>>>(
      inp, hid,
      (const float*)d_in[3], (const float*)d_in[4],
      (const float*)d_in[5], (const float*)d_in[6],
      (const float*)d_in[7], (const float*)d_in[8],
      (const float*)d_in[9], (const float*)d_in[10],
      actB, wB);
  lstm_gemm<<<dim3(1024), dim3(512), 0, stream>>>(
      actB, wB, cprev,
      (const float*)d_in[11], (const float*)d_in[12],
      (const float*)d_in[13], (const float*)d_in[14],
      (float*)d_out);
}

// Round 15
// 555.692 us; speedup vs baseline: 1.0994x; 1.0030x over previous
//
#include <hip/hip_runtime.h>

#define B_ROWS 8192
#define IN_DIM 2048
#define H_DIM  2048
#define K_DIM  4096              // IN + H
#define CH_OFF (B_ROWS * H_DIM)  // offset of h_t in d_out
#define NKS    (K_DIM / 64)      // 64 K-steps of depth 64
#define NIT    (NKS / 2)         // 32 iterations, 2 K-steps each

typedef __attribute__((ext_vector_type(8))) short bf16x8;
typedef __attribute__((ext_vector_type(8))) short short8;
typedef __attribute__((ext_vector_type(4))) float f32x4;

// fp32 -> bf16 round-to-nearest-even
static __device__ __forceinline__ unsigned short f2bf(float f) {
  union { float f; unsigned u; } v; v.f = f;
  unsigned r = v.u + 0x7fffu + ((v.u >> 16) & 1u);
  return (unsigned short)(r >> 16);
}

// async 16B global -> LDS (wave-uniform base + lane*16 on the LDS side).
// offset operand MUST be 0 (R7/R8/R9 NaNs with non-zero offsets).
static __device__ __forceinline__ void load_lds16(const void* g, void* l) {
  __builtin_amdgcn_global_load_lds(
      (const __attribute__((address_space(1))) unsigned int*)(unsigned long long)(uintptr_t)g,
      (__attribute__((address_space(3))) unsigned int*)(unsigned int)(uintptr_t)l,
      16, 0, 0);
}

// ---------------------------------------------------------------------------
// Merged pack kernel.
// blocks [0, 16384): pack [input|hidden] fp32 -> A bf16 [8192][4096]
// blocks [16384, 24576): pack+transpose weights ->
//   WT[n][k] bf16, n = (h>>4)*64 + gate*16 + (h&15)
// ---------------------------------------------------------------------------
__global__ __launch_bounds__(256) void pack_all(
    const float* __restrict__ inp, const float* __restrict__ hid,
    const float* __restrict__ wi0, const float* __restrict__ wi1,
    const float* __restrict__ wi2, const float* __restrict__ wi3,
    const float* __restrict__ wh0, const float* __restrict__ wh1,
    const float* __restrict__ wh2, const float* __restrict__ wh3,
    short* __restrict__ actB, short* __restrict__ wB) {
  __shared__ float tileS[64][65];
  int t = threadIdx.x;
  if (blockIdx.x < 16384) {
    int idx = blockIdx.x * 256 + t;
    int m = idx >> 9;
    int k = (idx & 511) * 8;
    const float* s = (k < IN_DIM) ? (inp + m * IN_DIM + k)
                                  : (hid + m * H_DIM + (k - IN_DIM));
    float4 a = *(const float4*)s;
    float4 c = *(const float4*)(s + 4);
    short8 o;
    o[0] = (short)f2bf(a.x); o[1] = (short)f2bf(a.y);
    o[2] = (short)f2bf(a.z); o[3] = (short)f2bf(a.w);
    o[4] = (short)f2bf(c.x); o[5] = (short)f2bf(c.y);
    o[6] = (short)f2bf(c.z); o[7] = (short)f2bf(c.w);
    *(short8*)(actB + (size_t)idx * 8) = o;
    return;
  }
  int b = blockIdx.x - 16384;
  int w = b >> 10;
  int tile = b & 1023;
  int tk = tile >> 5;
  int th = tile & 31;
  const float* src;
  switch (w) {
    case 0: src = wi0; break; case 1: src = wi1; break;
    case 2: src = wi2; break; case 3: src = wi3; break;
    case 4: src = wh0; break; case 5: src = wh1; break;
    case 6: src = wh2; break; default: src = wh3; break;
  }
  int g = w & 3, half = w >> 2;
  #pragma unroll
  for (int it = 0; it < 4; ++it) {
    int idx = it * 256 + t;
    int sr = idx >> 4, sc = idx & 15;
    float4 v = *(const float4*)(src + (tk * 64 + sr) * H_DIM + th * 64 + sc * 4);
    tileS[sr][sc * 4 + 0] = v.x; tileS[sr][sc * 4 + 1] = v.y;
    tileS[sr][sc * 4 + 2] = v.z; tileS[sr][sc * 4 + 3] = v.w;
  }
  __syncthreads();
  #pragma unroll
  for (int it = 0; it < 2; ++it) {
    int idx = it * 256 + t;
    int orow = idx >> 3;
    int okg = idx & 7;
    short8 o;
    #pragma unroll
    for (int j = 0; j < 8; ++j) o[j] = (short)f2bf(tileS[okg * 8 + j][orow]);
    int hg = th * 64 + orow;
    int n = (hg >> 4) * 64 + g * 16 + (hg & 15);
    int off = n * K_DIM + half * IN_DIM + tk * 64 + okg * 8;
    *(short8*)(wB + off) = o;
  }
}

// ---------------------------------------------------------------------------
// Fused GEMM (bf16 16x16x32 MFMA) + LSTM epilogue — R10's 8-phase quadrant
// schedule; blanket lgkmcnt(0)/sched_barrier pins REMOVED (compiler emits
// counted lgkm waits for the tracked frag dependencies), batched cprev.
// ---------------------------------------------------------------------------
__global__ __launch_bounds__(512, 2) void lstm_gemm(
    const short* __restrict__ actB,   // [8192][4096] bf16
    const short* __restrict__ wB,     // [8192][4096] bf16 packed W^T
    const float* __restrict__ cprev,
    const float* __restrict__ bi_p, const float* __restrict__ bf_p,
    const float* __restrict__ bg_p, const float* __restrict__ bo_p,
    float* __restrict__ out) {
  // buf: 256 rows x 64 k x 2B = 32 KB; row = 128B = 8 chunks of 16B,
  // phys chunk = logical ^ (row & 7). 2 bufs per operand.
  __shared__ __align__(16) short As[2][16384];   // 64 KB
  __shared__ __align__(16) short Bs[2][16384];   // 64 KB

  int bid = blockIdx.x;
  int swz = (bid & 7) * 128 + (bid >> 3);   // bijective XCD swizzle (1024%8==0)
  int mblk = swz >> 5, nblk = swz & 31;
  int m0 = mblk * 256;
  int n0 = nblk * 256;

  int t = threadIdx.x;
  int lane = t & 63, wid = t >> 6;
  int wm = wid >> 2, wn = wid & 3;          // 2M x 4N wave grid
  int q = lane >> 4, cl = lane & 15;

  // ---- staging thread map: idx = ld*512+t covers one half-tile (128r x 8c)
  int rpl0 = t >> 3, c0s = t & 7;
  int cu0 = c0s ^ (rpl0 & 7);
  int idx1 = 512 + t;
  int rpl1 = idx1 >> 3, c1s = idx1 & 7;
  int cu1 = c1s ^ (rpl1 & 7);
  const short* aG0 = actB + (size_t)(m0 + rpl0) * K_DIM + cu0 * 8;
  const short* aG1 = actB + (size_t)(m0 + rpl1) * K_DIM + cu1 * 8;
  const short* bG0 = wB   + (size_t)(n0 + rpl0) * K_DIM + cu0 * 8;
  const short* bG1 = wB   + (size_t)(n0 + rpl1) * K_DIM + cu1 * 8;
  char* aL0 = (char*)&As[0][0] + t * 16;
  char* aL1 = (char*)&As[0][0] + idx1 * 16;
  char* bL0 = (char*)&Bs[0][0] + t * 16;
  char* bL1 = (char*)&Bs[0][0] + idx1 * 16;

  auto stgA = [&](int ks, int h, int buf) {   // h,buf compile-time at call
    load_lds16(aG0 + h * (128 * K_DIM) + ks * 64, aL0 + buf * 32768 + h * 16384);
    load_lds16(aG1 + h * (128 * K_DIM) + ks * 64, aL1 + buf * 32768 + h * 16384);
  };
  auto stgB = [&](int ks, int h, int buf) {
    load_lds16(bG0 + h * (128 * K_DIM) + ks * 64, bL0 + buf * 32768 + h * 16384);
    load_lds16(bG1 + h * (128 * K_DIM) + ks * 64, bL1 + buf * 32768 + h * 16384);
  };

  // ---- fragment read bases: row r byte = r*128, chunk = (s*4+q)^(r&7) ----
  int cc0 = (q ^ (cl & 7)) * 16;
  const char* aRd0 = (const char*)&As[0][0] + wm * 16384 + cl * 128 + cc0;
  const char* aRd1 = (const char*)&As[0][0] + wm * 16384 + cl * 128 + (cc0 ^ 64);
  const char* bRd0 = (const char*)&Bs[0][0] + wn * 8192 + cl * 128 + cc0;
  const char* bRd1 = (const char*)&Bs[0][0] + wn * 8192 + cl * 128 + (cc0 ^ 64);

  auto rdA = [&](int buf, int mi, int s) -> bf16x8 {   // all args compile-time
    return *(const bf16x8*)((s ? aRd1 : aRd0) + buf * 32768 + mi * 2048);
  };
  auto rdB = [&](int buf, int ni, int s) -> bf16x8 {
    return *(const bf16x8*)((s ? bRd1 : bRd0) + buf * 32768 + ni * 2048);
  };

  f32x4 zero = {0.f, 0.f, 0.f, 0.f};
  f32x4 acc[8][4];
  #pragma unroll
  for (int mi = 0; mi < 8; ++mi)
    #pragma unroll
    for (int ni = 0; ni < 4; ++ni) acc[mi][ni] = zero;

  bf16x8 aLo[4][2], aHi[4][2], b0f[2][2], b1f[2][2];

  auto QUAD = [&](bf16x8 (&af)[4][2], bf16x8 (&bf)[2][2], int mb, int nb) {
    __builtin_amdgcn_s_setprio(1);
    #pragma unroll
    for (int mi = 0; mi < 4; ++mi)
      #pragma unroll
      for (int ni = 0; ni < 2; ++ni)
        #pragma unroll
        for (int s = 0; s < 2; ++s)
          acc[mb + mi][nb + ni] = __builtin_amdgcn_mfma_f32_16x16x32_bf16(
              af[mi][s], bf[ni][s], acc[mb + mi][nb + ni], 0, 0, 0);
    __builtin_amdgcn_s_setprio(0);
  };

  // One K-step (4 phases). bufC = current buffer; bufN = next K-step's.
  // b0f for THIS step preloaded in the previous P_d (or prologue).
  // ds_reads are compiler-visible: counted lgkm waits are emitted before
  // the consuming MFMA automatically (no blanket drains, no order pins).
  auto halfK = [&](int bufC, int bufN, int ksA_, int bufA_, int ksB_, int bufB_) {
    // -- P_a: read A-lo(8); stage A-h0; Q00(aLo,b0) --
    #pragma unroll
    for (int mi = 0; mi < 4; ++mi) {
      aLo[mi][0] = rdA(bufC, mi, 0); aLo[mi][1] = rdA(bufC, mi, 1);
    }
    stgA(ksA_, 0, bufA_);
    asm volatile("s_waitcnt lgkmcnt(8)" ::: "memory");
    __builtin_amdgcn_s_barrier();
    QUAD(aLo, b0f, 0, 0);
    __builtin_amdgcn_s_barrier();
    // -- P_b: read B1(4); stage A-h1; Q01(aLo,b1) --
    #pragma unroll
    for (int ni = 0; ni < 2; ++ni) {
      b1f[ni][0] = rdB(bufC, ni + 2, 0); b1f[ni][1] = rdB(bufC, ni + 2, 1);
    }
    stgA(ksA_, 1, bufA_);
    __builtin_amdgcn_s_barrier();
    QUAD(aLo, b1f, 0, 2);
    __builtin_amdgcn_s_barrier();
    // -- P_c: read A-hi(8); stage B-h0; Q11(aHi,b1) --
    #pragma unroll
    for (int mi = 0; mi < 4; ++mi) {
      aHi[mi][0] = rdA(bufC, mi + 4, 0); aHi[mi][1] = rdA(bufC, mi + 4, 1);
    }
    stgB(ksB_, 0, bufB_);
    __builtin_amdgcn_s_barrier();
    QUAD(aHi, b1f, 4, 2);
    __builtin_amdgcn_s_barrier();
    // -- P_d: stage B-h1; vmcnt(4) publishes bufN; Q10(aHi,b0);
    //         preload next step's b0 from bufN (ds_reads are memory ops ->
    //         pinned after the publish barrier by the "memory" clobber) --
    stgB(ksB_, 1, bufB_);
    asm volatile("s_waitcnt vmcnt(4)" ::: "memory");
    __builtin_amdgcn_s_barrier();
    QUAD(aHi, b0f, 4, 0);
    #pragma unroll
    for (int ni = 0; ni < 2; ++ni) {
      b0f[ni][0] = rdB(bufN, ni, 0); b0f[ni][1] = rdB(bufN, ni, 1);
    }
    __builtin_amdgcn_s_barrier();
  };

  // prologue: stage B(0), A(0) -> buf0; B(1) -> buf1; publish tile 0
  stgB(0, 0, 0); stgB(0, 1, 0);
  stgA(0, 0, 0); stgA(0, 1, 0);
  stgB(1, 0, 1); stgB(1, 1, 1);
  asm volatile("s_waitcnt vmcnt(4)" ::: "memory");
  __builtin_amdgcn_s_barrier();
  // preload b0 for K-step 0 (tile 0, buf0)
  #pragma unroll
  for (int ni = 0; ni < 2; ++ni) {
    b0f[ni][0] = rdB(0, ni, 0); b0f[ni][1] = rdB(0, ni, 1);
  }

  #pragma unroll 1
  for (int i = 0; i < NIT; ++i) {
    int ks1 = 2 * i + 1;
    int ksA = 2 * i + 2; if (ksA > NKS - 1) ksA = NKS - 1;
    int ksB = 2 * i + 3; if (ksB > NKS - 1) ksB = NKS - 1;
    halfK(0, 1, ks1, 1, ksA, 0);   // K-step 2i   (buf0); stage A(2i+1), B(2i+2)
    halfK(1, 0, ksA, 0, ksB, 1);   // K-step 2i+1 (buf1); stage A(2i+2), B(2i+3)
  }

  // ---- epilogue: batch cprev loads so they fly during the vmcnt drain ----
  int hg = (nblk * 4 + wn) * 16 + cl;
  int mbase = m0 + wm * 128;
  float cp[8][4];
  #pragma unroll
  for (int mi = 0; mi < 8; ++mi)
    #pragma unroll
    for (int r = 0; r < 4; ++r)
      cp[mi][r] = cprev[(size_t)(mbase + mi * 16 + q * 4 + r) * H_DIM + hg];
  asm volatile("s_waitcnt vmcnt(0)" ::: "memory");   // retire garbage stages

  float vbi = bi_p[hg], vbf = bf_p[hg], vbg = bg_p[hg], vbo = bo_p[hg];
  #pragma unroll
  for (int mi = 0; mi < 8; ++mi) {
    #pragma unroll
    for (int r = 0; r < 4; ++r) {
      int mg = mbase + mi * 16 + q * 4 + r;
      float pi = acc[mi][0][r] + vbi;
      float pf = acc[mi][1][r] + vbf;
      float pg = acc[mi][2][r] + vbg;
      float po = acc[mi][3][r] + vbo;
      float iv = 1.f / (1.f + __expf(-pi));
      float fv = 1.f / (1.f + __expf(-pf));
      float gv = 1.f - 2.f / (__expf(2.f * pg) + 1.f);
      float ov = 1.f / (1.f + __expf(-po));
      float cv = fv * cp[mi][r] + iv * gv;
      float tc = 1.f - 2.f / (__expf(2.f * cv) + 1.f);
      out[(size_t)mg * H_DIM + hg] = cv;
      out[CH_OFF + (size_t)mg * H_DIM + hg] = ov * tc;
    }
  }
}

extern "C" void kernel_launch(void* const* d_in, const int* in_sizes, int n_in,
                              void* d_out, int out_size, void* d_ws, size_t ws_size,
                              hipStream_t stream) {
  const float* inp   = (const float*)d_in[0];
  const float* hid   = (const float*)d_in[1];
  const float* cprev = (const float*)d_in[2];
  short* actB = (short*)d_ws;
  short* wB   = actB + (size_t)B_ROWS * K_DIM;

  pack_all<<<dim3(24576), dim3(256), 0, stream>>>(
      inp, hid,
      (const float*)d_in[3], (const float*)d_in[4],
      (const float*)d_in[5], (const float*)d_in[6],
      (const float*)d_in[7], (const float*)d_in[8],
      (const float*)d_in[9], (const float*)d_in[10],
      actB, wB);
  lstm_gemm<<<dim3(1024), dim3(512), 0, stream>>>(
      actB, wB, cprev,
      (const float*)d_in[11], (const float*)d_in[12],
      (const float*)d_in[13], (const float*)d_in[14],
      (float*)d_out);
}

// Round 17
// 555.283 us; speedup vs baseline: 1.1002x; 1.0007x over previous
//
#include <hip/hip_runtime.h>

#define B_ROWS 8192
#define IN_DIM 2048
#define H_DIM  2048
#define K_DIM  4096              // IN + H
#define CH_OFF (B_ROWS * H_DIM)  // offset of h_t in d_out
#define NKS    (K_DIM / 64)      // 64 K-steps of depth 64
#define NIT    (NKS / 2)         // 32 iterations, 2 K-steps each

typedef __attribute__((ext_vector_type(8))) short bf16x8;
typedef __attribute__((ext_vector_type(8))) short short8;
typedef __attribute__((ext_vector_type(4))) float f32x4;

// fp32 -> bf16 round-to-nearest-even
static __device__ __forceinline__ unsigned short f2bf(float f) {
  union { float f; unsigned u; } v; v.f = f;
  unsigned r = v.u + 0x7fffu + ((v.u >> 16) & 1u);
  return (unsigned short)(r >> 16);
}

// async 16B global -> LDS (wave-uniform base + lane*16 on the LDS side).
// offset operand MUST be 0 (R7/R8/R9 NaNs with non-zero offsets).
static __device__ __forceinline__ void load_lds16(const void* g, void* l) {
  __builtin_amdgcn_global_load_lds(
      (const __attribute__((address_space(1))) unsigned int*)(unsigned long long)(uintptr_t)g,
      (__attribute__((address_space(3))) unsigned int*)(unsigned int)(uintptr_t)l,
      16, 0, 0);
}

// ---------------------------------------------------------------------------
// Merged pack kernel.
// blocks [0, 16384): pack [input|hidden] fp32 -> A bf16 [8192][4096]
// blocks [16384, 24576): pack+transpose weights ->
//   WT[n][k] bf16, n = (h>>4)*64 + gate*16 + (h&15)
// ---------------------------------------------------------------------------
__global__ __launch_bounds__(256) void pack_all(
    const float* __restrict__ inp, const float* __restrict__ hid,
    const float* __restrict__ wi0, const float* __restrict__ wi1,
    const float* __restrict__ wi2, const float* __restrict__ wi3,
    const float* __restrict__ wh0, const float* __restrict__ wh1,
    const float* __restrict__ wh2, const float* __restrict__ wh3,
    short* __restrict__ actB, short* __restrict__ wB) {
  __shared__ float tileS[64][65];
  int t = threadIdx.x;
  if (blockIdx.x < 16384) {
    int idx = blockIdx.x * 256 + t;
    int m = idx >> 9;
    int k = (idx & 511) * 8;
    const float* s = (k < IN_DIM) ? (inp + m * IN_DIM + k)
                                  : (hid + m * H_DIM + (k - IN_DIM));
    float4 a = *(const float4*)s;
    float4 c = *(const float4*)(s + 4);
    short8 o;
    o[0] = (short)f2bf(a.x); o[1] = (short)f2bf(a.y);
    o[2] = (short)f2bf(a.z); o[3] = (short)f2bf(a.w);
    o[4] = (short)f2bf(c.x); o[5] = (short)f2bf(c.y);
    o[6] = (short)f2bf(c.z); o[7] = (short)f2bf(c.w);
    *(short8*)(actB + (size_t)idx * 8) = o;
    return;
  }
  int b = blockIdx.x - 16384;
  int w = b >> 10;
  int tile = b & 1023;
  int tk = tile >> 5;
  int th = tile & 31;
  const float* src;
  switch (w) {
    case 0: src = wi0; break; case 1: src = wi1; break;
    case 2: src = wi2; break; case 3: src = wi3; break;
    case 4: src = wh0; break; case 5: src = wh1; break;
    case 6: src = wh2; break; default: src = wh3; break;
  }
  int g = w & 3, half = w >> 2;
  #pragma unroll
  for (int it = 0; it < 4; ++it) {
    int idx = it * 256 + t;
    int sr = idx >> 4, sc = idx & 15;
    float4 v = *(const float4*)(src + (tk * 64 + sr) * H_DIM + th * 64 + sc * 4);
    tileS[sr][sc * 4 + 0] = v.x; tileS[sr][sc * 4 + 1] = v.y;
    tileS[sr][sc * 4 + 2] = v.z; tileS[sr][sc * 4 + 3] = v.w;
  }
  __syncthreads();
  #pragma unroll
  for (int it = 0; it < 2; ++it) {
    int idx = it * 256 + t;
    int orow = idx >> 3;
    int okg = idx & 7;
    short8 o;
    #pragma unroll
    for (int j = 0; j < 8; ++j) o[j] = (short)f2bf(tileS[okg * 8 + j][orow]);
    int hg = th * 64 + orow;
    int n = (hg >> 4) * 64 + g * 16 + (hg & 15);
    int off = n * K_DIM + half * IN_DIM + tk * 64 + okg * 8;
    *(short8*)(wB + off) = o;
  }
}

// ---------------------------------------------------------------------------
// Fused GEMM (bf16 16x16x32 MFMA) + LSTM epilogue — 8-phase quadrant
// schedule, DEPTH-3 staging with WAR-correct placement:
//   P_a: stage A(j+1)h1->bufN   (bufN A-h1 last read: step j-1 P_c)
//   P_c: stage B(j+2)h0->bufC   (bufC B-h0 last read: P_b)
//   P_d: stage A(j+2)h0->bufC   (bufC A-h0 last read: P_c  <- R16's bug)
//        stage B(j+2)h1->bufC   (bufC B-h1 last read: P_b)
//        vmcnt(6): 14 in flight -> retires 8 = tile j+1 complete.
// ---------------------------------------------------------------------------
__global__ __launch_bounds__(512, 2) void lstm_gemm(
    const short* __restrict__ actB,   // [8192][4096] bf16
    const short* __restrict__ wB,     // [8192][4096] bf16 packed W^T
    const float* __restrict__ cprev,
    const float* __restrict__ bi_p, const float* __restrict__ bf_p,
    const float* __restrict__ bg_p, const float* __restrict__ bo_p,
    float* __restrict__ out) {
  // buf: 256 rows x 64 k x 2B = 32 KB; row = 128B = 8 chunks of 16B,
  // phys chunk = logical ^ (row & 7). 2 bufs per operand.
  __shared__ __align__(16) short As[2][16384];   // 64 KB
  __shared__ __align__(16) short Bs[2][16384];   // 64 KB

  int bid = blockIdx.x;
  int swz = (bid & 7) * 128 + (bid >> 3);   // bijective XCD swizzle (1024%8==0)
  int mblk = swz >> 5, nblk = swz & 31;
  int m0 = mblk * 256;
  int n0 = nblk * 256;

  int t = threadIdx.x;
  int lane = t & 63, wid = t >> 6;
  int wm = wid >> 2, wn = wid & 3;          // 2M x 4N wave grid
  int q = lane >> 4, cl = lane & 15;

  // ---- staging thread map: idx = ld*512+t covers one half-tile (128r x 8c)
  int rpl0 = t >> 3, c0s = t & 7;
  int cu0 = c0s ^ (rpl0 & 7);
  int idx1 = 512 + t;
  int rpl1 = idx1 >> 3, c1s = idx1 & 7;
  int cu1 = c1s ^ (rpl1 & 7);
  const short* aG0 = actB + (size_t)(m0 + rpl0) * K_DIM + cu0 * 8;
  const short* aG1 = actB + (size_t)(m0 + rpl1) * K_DIM + cu1 * 8;
  const short* bG0 = wB   + (size_t)(n0 + rpl0) * K_DIM + cu0 * 8;
  const short* bG1 = wB   + (size_t)(n0 + rpl1) * K_DIM + cu1 * 8;
  char* aL0 = (char*)&As[0][0] + t * 16;
  char* aL1 = (char*)&As[0][0] + idx1 * 16;
  char* bL0 = (char*)&Bs[0][0] + t * 16;
  char* bL1 = (char*)&Bs[0][0] + idx1 * 16;

  auto stgA = [&](int ks, int h, int buf) {   // h,buf compile-time at call
    load_lds16(aG0 + h * (128 * K_DIM) + ks * 64, aL0 + buf * 32768 + h * 16384);
    load_lds16(aG1 + h * (128 * K_DIM) + ks * 64, aL1 + buf * 32768 + h * 16384);
  };
  auto stgB = [&](int ks, int h, int buf) {
    load_lds16(bG0 + h * (128 * K_DIM) + ks * 64, bL0 + buf * 32768 + h * 16384);
    load_lds16(bG1 + h * (128 * K_DIM) + ks * 64, bL1 + buf * 32768 + h * 16384);
  };

  // ---- fragment read bases: row r byte = r*128, chunk = (s*4+q)^(r&7) ----
  int cc0 = (q ^ (cl & 7)) * 16;
  const char* aRd0 = (const char*)&As[0][0] + wm * 16384 + cl * 128 + cc0;
  const char* aRd1 = (const char*)&As[0][0] + wm * 16384 + cl * 128 + (cc0 ^ 64);
  const char* bRd0 = (const char*)&Bs[0][0] + wn * 8192 + cl * 128 + cc0;
  const char* bRd1 = (const char*)&Bs[0][0] + wn * 8192 + cl * 128 + (cc0 ^ 64);

  auto rdA = [&](int buf, int mi, int s) -> bf16x8 {   // all args compile-time
    return *(const bf16x8*)((s ? aRd1 : aRd0) + buf * 32768 + mi * 2048);
  };
  auto rdB = [&](int buf, int ni, int s) -> bf16x8 {
    return *(const bf16x8*)((s ? bRd1 : bRd0) + buf * 32768 + ni * 2048);
  };

  f32x4 zero = {0.f, 0.f, 0.f, 0.f};
  f32x4 acc[8][4];
  #pragma unroll
  for (int mi = 0; mi < 8; ++mi)
    #pragma unroll
    for (int ni = 0; ni < 4; ++ni) acc[mi][ni] = zero;

  bf16x8 aLo[4][2], aHi[4][2], b0f[2][2], b1f[2][2];

  auto QUAD = [&](bf16x8 (&af)[4][2], bf16x8 (&bf)[2][2], int mb, int nb) {
    __builtin_amdgcn_s_setprio(1);
    #pragma unroll
    for (int mi = 0; mi < 4; ++mi)
      #pragma unroll
      for (int ni = 0; ni < 2; ++ni)
        #pragma unroll
        for (int s = 0; s < 2; ++s)
          acc[mb + mi][nb + ni] = __builtin_amdgcn_mfma_f32_16x16x32_bf16(
              af[mi][s], bf[ni][s], acc[mb + mi][nb + ni], 0, 0, 0);
    __builtin_amdgcn_s_setprio(0);
  };

  // One K-step j (4 phases). bufC = j&1, bufN = (j+1)&1.
  // ksN = clamp(j+1), ksNN = clamp(j+2). Stage plan in kernel header.
  auto halfK = [&](int bufC, int bufN, int ksN, int ksNN) {
    // -- P_a: read A-lo(8); stage A(j+1)h1 -> bufN; Q00(aLo,b0) --
    #pragma unroll
    for (int mi = 0; mi < 4; ++mi) {
      aLo[mi][0] = rdA(bufC, mi, 0); aLo[mi][1] = rdA(bufC, mi, 1);
    }
    stgA(ksN, 1, bufN);
    __builtin_amdgcn_s_barrier();
    QUAD(aLo, b0f, 0, 0);
    __builtin_amdgcn_s_barrier();
    // -- P_b: read B1(4); Q01(aLo,b1) --
    #pragma unroll
    for (int ni = 0; ni < 2; ++ni) {
      b1f[ni][0] = rdB(bufC, ni + 2, 0); b1f[ni][1] = rdB(bufC, ni + 2, 1);
    }
    __builtin_amdgcn_s_barrier();
    QUAD(aLo, b1f, 0, 2);
    __builtin_amdgcn_s_barrier();
    // -- P_c: read A-hi(8); stage B(j+2)h0 -> bufC; Q11(aHi,b1) --
    #pragma unroll
    for (int mi = 0; mi < 4; ++mi) {
      aHi[mi][0] = rdA(bufC, mi + 4, 0); aHi[mi][1] = rdA(bufC, mi + 4, 1);
    }
    stgB(ksNN, 0, bufC);
    __builtin_amdgcn_s_barrier();
    QUAD(aHi, b1f, 4, 2);
    __builtin_amdgcn_s_barrier();
    // -- P_d: stage A(j+2)h0 + B(j+2)h1 -> bufC (A-h0 readers done at P_c);
    //         vmcnt(6) retires tile j+1; Q10(aHi,b0); preload next b0 --
    stgA(ksNN, 0, bufC);
    stgB(ksNN, 1, bufC);
    asm volatile("s_waitcnt vmcnt(6)" ::: "memory");
    __builtin_amdgcn_s_barrier();
    QUAD(aHi, b0f, 4, 0);
    #pragma unroll
    for (int ni = 0; ni < 2; ++ni) {
      b0f[ni][0] = rdB(bufN, ni, 0); b0f[ni][1] = rdB(bufN, ni, 1);
    }
    __builtin_amdgcn_s_barrier();
  };

  // prologue: tile0 -> buf0 (8 loads); A(1)h0, B(1)h0, B(1)h1 -> buf1 (6);
  // vmcnt(6) retires tile 0 exactly, leaving tile 1's first 3 half-tiles.
  stgA(0, 0, 0); stgA(0, 1, 0); stgB(0, 0, 0); stgB(0, 1, 0);
  stgB(1, 0, 1); stgA(1, 0, 1); stgB(1, 1, 1);
  asm volatile("s_waitcnt vmcnt(6)" ::: "memory");
  __builtin_amdgcn_s_barrier();
  // preload b0 for K-step 0 (tile 0, buf0)
  #pragma unroll
  for (int ni = 0; ni < 2; ++ni) {
    b0f[ni][0] = rdB(0, ni, 0); b0f[ni][1] = rdB(0, ni, 1);
  }

  #pragma unroll 1
  for (int i = 0; i < NIT; ++i) {
    int j0 = 2 * i, j1 = 2 * i + 1;
    int ksN0 = j0 + 1;                       // <= 63 always
    int ksNN0 = j0 + 2; if (ksNN0 > NKS - 1) ksNN0 = NKS - 1;
    int ksN1 = j1 + 1;  if (ksN1 > NKS - 1) ksN1 = NKS - 1;
    int ksNN1 = j1 + 2; if (ksNN1 > NKS - 1) ksNN1 = NKS - 1;
    halfK(0, 1, ksN0, ksNN0);   // K-step 2i   (buf0)
    halfK(1, 0, ksN1, ksNN1);   // K-step 2i+1 (buf1)
  }

  // ---- epilogue: batch cprev loads so they fly during the vmcnt drain ----
  int hg = (nblk * 4 + wn) * 16 + cl;
  int mbase = m0 + wm * 128;
  float cp[8][4];
  #pragma unroll
  for (int mi = 0; mi < 8; ++mi)
    #pragma unroll
    for (int r = 0; r < 4; ++r)
      cp[mi][r] = cprev[(size_t)(mbase + mi * 16 + q * 4 + r) * H_DIM + hg];
  asm volatile("s_waitcnt vmcnt(0)" ::: "memory");   // retire garbage stages

  float vbi = bi_p[hg], vbf = bf_p[hg], vbg = bg_p[hg], vbo = bo_p[hg];
  #pragma unroll
  for (int mi = 0; mi < 8; ++mi) {
    #pragma unroll
    for (int r = 0; r < 4; ++r) {
      int mg = mbase + mi * 16 + q * 4 + r;
      float pi = acc[mi][0][r] + vbi;
      float pf = acc[mi][1][r] + vbf;
      float pg = acc[mi][2][r] + vbg;
      float po = acc[mi][3][r] + vbo;
      float iv = 1.f / (1.f + __expf(-pi));
      float fv = 1.f / (1.f + __expf(-pf));
      float gv = 1.f - 2.f / (__expf(2.f * pg) + 1.f);
      float ov = 1.f / (1.f + __expf(-po));
      float cv = fv * cp[mi][r] + iv * gv;
      float tc = 1.f - 2.f / (__expf(2.f * cv) + 1.f);
      out[(size_t)mg * H_DIM + hg] = cv;
      out[CH_OFF + (size_t)mg * H_DIM + hg] = ov * tc;
    }
  }
}

extern "C" void kernel_launch(void* const* d_in, const int* in_sizes, int n_in,
                              void* d_out, int out_size, void* d_ws, size_t ws_size,
                              hipStream_t stream) {
  const float* inp   = (const float*)d_in[0];
  const float* hid   = (const float*)d_in[1];
  const float* cprev = (const float*)d_in[2];
  short* actB = (short*)d_ws;
  short* wB   = actB + (size_t)B_ROWS * K_DIM;

  pack_all<<<dim3(24576), dim3(256), 0, stream>>>(
      inp, hid,
      (const float*)d_in[3], (const float*)d_in[4],
      (const float*)d_in[5], (const float*)d_in[6],
      (const float*)d_in[7], (const float*)d_in[8],
      (const float*)d_in[9], (const float*)d_in[10],
      actB, wB);
  lstm_gemm<<<dim3(1024), dim3(512), 0, stream>>>(
      actB, wB, cprev,
      (const float*)d_in[11], (const float*)d_in[12],
      (const float*)d_in[13], (const float*)d_in[14],
      (float*)d_out);
}